// Round 11
// baseline (1195.197 us; speedup 1.0000x reference)
//
#include <hip/hip_runtime.h>
#include <hip/hip_cooperative_groups.h>
#include <cstddef>
#include <cstdint>

namespace cg = cooperative_groups;

typedef __attribute__((ext_vector_type(4))) float f32x4;
typedef __attribute__((ext_vector_type(8))) short short8;

#define HID 128
#define NK1 -1.4426950408889634f  // -log2(e)
#define PK2 2.8853900817779268f   // +2*log2(e)

// LDS-only barrier: no vmcnt(0) drain.
#define BAR_LGKM() __asm__ volatile("s_waitcnt lgkmcnt(0)\ns_barrier" ::: "memory")
// depth-2 prefetch fence: retire gather(t), keep gather(t+1) in flight
#define STEP_BAR2() __asm__ volatile("s_waitcnt vmcnt(2) lgkmcnt(0)\ns_barrier" ::: "memory")

__device__ __forceinline__ short f2bf(float f) {
  unsigned u = __builtin_bit_cast(unsigned, f);
  u += 0x7FFFu + ((u >> 16) & 1u);
  return (short)(u >> 16);
}
__device__ __forceinline__ unsigned pack_bf2(float a, float b) {
  unsigned ua = __builtin_bit_cast(unsigned, a) + 0x8000u;
  unsigned ub = __builtin_bit_cast(unsigned, b) + 0x8000u;
  return __builtin_amdgcn_perm(ub, ua, 0x07060302u);
}

// folded LSTM cell: inputs are PRE-SCALED pre-activations
// si,sf,so = -log2e*(gate), sg = 2log2e*(g). 5 exp2 + 2 rcp (algebraic min).
__device__ __forceinline__ float lstm_elem(float si, float sf, float sg, float so, float& c) {
  float Ei = __builtin_amdgcn_exp2f(si);
  float Ef = __builtin_amdgcn_exp2f(sf);
  float Tg = __builtin_amdgcn_exp2f(sg);
  float Eo = __builtin_amdgcn_exp2f(so);
  float u = 1.0f + Ei, w = 1.0f + Ef, v = Tg + 1.0f, Tm = Tg - 1.0f;
  float t0 = u * v;
  float num = __builtin_fmaf(c, t0, w * Tm);
  float cn = num * __builtin_amdgcn_rcpf(w * t0);
  c = cn;
  float Tc = __builtin_amdgcn_exp2f(PK2 * cn);
  return (Tc - 1.0f) * __builtin_amdgcn_rcpf((1.0f + Eo) * (Tc + 1.0f));
}

#define ASTR 136
#define NPB 16
#define PSTR 520
#define HSTR 152
#define LSTM_LDS_BYTES ((3 * NPB * PSTR + 2 * NPB * HSTR) * 2 + 256 * 4 + 16)  // 60688

struct KParams {
  const float* x;
  const int* src;
  const float* Wih[3]; const float* Whh[3];
  const float* bih[3]; const float* bhh[3];
  const float* Wl[3];  const float* bl[3]; const float* Wr[3];
  short* curA; short* curB; short* Pbuf;
  short* wihB[3]; short* whhB[3]; short* wlB[3]; short* wrB[3];
  float* bsum[3];
  int* tctr;
  float* outF;
  int M, ntiles, nltiles;
};

// ============ ONE cooperative persistent kernel: conv + 3x(pgemm, lstm) ======
// Replaces 7 dispatches (and their launch bubbles) with 6 grid.sync()s.
// Phase bodies are the R8/R10-proven code verbatim; lstm phase unchanged.
__global__ __launch_bounds__(512, 4) void fused_all(KParams p) {
  extern __shared__ char smem[];
  const int tid = threadIdx.x;
  const int wave = tid >> 6, lane = tid & 63;
  const int quad = lane >> 4, nn = lane & 15;
  cg::grid_group grid = cg::this_grid();

  // ---------------- phase 0: conversions ----------------
  {
    const int gi = blockIdx.x * 512 + tid;
    const int gs = (int)gridDim.x * 512;
    if (gi < 8) p.tctr[gi] = 0;  // dynamic-tile counters (re-zeroed every replay)
    const int nx = p.M * HID;
    for (int i = gi; i < nx; i += gs) p.curA[i] = f2bf(p.x[i]);
#pragma unroll 1
    for (int l = 0; l < 3; ++l) {
      const int foK = ((l == 2) ? 64 : 128) * HID;
      for (int i = gi; i < 512 * HID; i += gs) {
        float sc = ((i >> 14) == 2) ? PK2 : NK1;  // gate = row>>7 = i>>14
        p.wihB[l][i] = f2bf(p.Wih[l][i] * sc);
        p.whhB[l][i] = f2bf(p.Whh[l][i] * sc);
      }
      for (int i = gi; i < foK; i += gs) {
        p.wlB[l][i] = f2bf(p.Wl[l][i]);
        p.wrB[l][i] = f2bf(p.Wr[l][i]);
      }
      for (int i = gi; i < 512; i += gs)
        p.bsum[l][i] = (p.bih[l][i] + p.bhh[l][i]) * (((i >> 7) == 2) ? PK2 : NK1);
    }
  }
  grid.sync();

  short* cur = p.curA;
  short* nxt = p.curB;

#pragma unroll 1
  for (int l = 0; l < 3; ++l) {
    // ---------------- pgemm phase: P = cur @ Wih^T + bias ----------------
    {
      short* ldsA = (short*)smem;                    // [32][ASTR]  8.7 KB
      float* ldsB = (float*)(smem + 32 * ASTR * 2);  // [512] bias  2 KB
      int* nextTp = (int*)(ldsB + 512);
      const short* A = cur;
      const short* W = p.wihB[l];
      short* outP = p.Pbuf;
      int* ctr = p.tctr + 3 + l;
      const int Mloc = p.M, ntl = p.ntiles;
      const int cbase = wave * 64;
      const int srow = wave * 4 + quad;
      const int scol = nn * 8;

      short8 wreg[4][4];
#pragma unroll
      for (int kt = 0; kt < 4; ++kt)
#pragma unroll
        for (int nt = 0; nt < 4; ++nt)
          wreg[kt][nt] = *(const short8*)(W + (size_t)(cbase + nt * 16 + nn) * HID + kt * 32 + quad * 8);
      ldsB[tid] = p.bsum[l][tid];  // bias cached in LDS (keeps VGPRs <= 128)

      int rt = blockIdx.x;
      short8 avn;
      {
        int r = rt * 32 + srow;
        if (r > Mloc - 1) r = Mloc - 1;
        avn = *(const short8*)(A + (size_t)r * HID + scol);
      }
#pragma unroll 1
      while (rt < ntl) {
        if (tid == 0) *nextTp = (int)gridDim.x + atomicAdd(ctr, 1);
        BAR_LGKM();  // WAR: prior ldsA reads done; nextT + ldsB visible
        *(short8*)(ldsA + srow * ASTR + scol) = avn;  // compiler waits vmcnt
        const int rn = *nextTp;
        if (rn < ntl) {
          int r = rn * 32 + srow;
          if (r > Mloc - 1) r = Mloc - 1;
          avn = *(const short8*)(A + (size_t)r * HID + scol);  // hidden under compute
        }
        BAR_LGKM();  // RAW: ldsA visible
        f32x4 acc[2][4];
#pragma unroll
        for (int nt = 0; nt < 4; ++nt) {
          f32x4 bv = *(const f32x4*)(ldsB + cbase + nt * 16 + quad * 4);
          acc[0][nt] = bv;
          acc[1][nt] = bv;
        }
#pragma unroll
        for (int kt = 0; kt < 4; ++kt) {
          short8 af0 = *(const short8*)(ldsA + nn * ASTR + kt * 32 + quad * 8);
          short8 af1 = *(const short8*)(ldsA + (16 + nn) * ASTR + kt * 32 + quad * 8);
#pragma unroll
          for (int nt = 0; nt < 4; ++nt) {
            acc[0][nt] = __builtin_amdgcn_mfma_f32_16x16x32_bf16(wreg[kt][nt], af0, acc[0][nt], 0, 0, 0);
            acc[1][nt] = __builtin_amdgcn_mfma_f32_16x16x32_bf16(wreg[kt][nt], af1, acc[1][nt], 0, 0, 0);
          }
        }
        const int row0 = rt * 32;
#pragma unroll
        for (int b = 0; b < 2; ++b) {
          int row = row0 + b * 16 + nn;
          if (row < Mloc) {
#pragma unroll
            for (int nt = 0; nt < 4; ++nt) {
              uint2 pk;
              pk.x = pack_bf2(acc[b][nt][0], acc[b][nt][1]);
              pk.y = pack_bf2(acc[b][nt][2], acc[b][nt][3]);
              *(uint2*)(outP + (size_t)row * 512 + cbase + nt * 16 + quad * 4) = pk;
            }
          }
        }
        rt = rn;
      }
    }
    grid.sync();

    // ---------------- lstm phase (R8 v9, unchanged) ----------------
    {
      short* Pb = (short*)smem;                 // [3][16][520]
      short* Hb = Pb + 3 * NPB * PSTR;          // [2][16][152]
      int* srcL = (int*)(Hb + 2 * NPB * HSTR);  // [256] byte offsets
      int* nextTp = srcL + 256;
      const short* Whh = p.whhB[l];
      const short* Wlw = p.wlB[l];
      const short* Wrw = p.wrB[l];
      const float* blw = p.bl[l];
      int* ctr = p.tctr + l;
      const int Mloc = p.M, ntl = p.nltiles;
      const int r0row = wave * 2, r1row = wave * 2 + 1;
      const char* Pbase = (const char*)p.Pbuf + lane * 16;
      const int FO = (l == 2) ? 64 : 128;

      short8 wreg[4][4];  // [kt][q]
#pragma unroll
      for (int kt = 0; kt < 4; ++kt)
#pragma unroll
        for (int q = 0; q < 4; ++q)
          wreg[kt][q] = *(const short8*)(Whh + (size_t)(q * 128 + wave * 16 + nn) * HID + kt * 32 + quad * 8);

      short8 ident;
#pragma unroll
      for (int e = 0; e < 8; ++e) ident[e] = (short)((quad * 8 + e == nn) ? 0x3F80 : 0);
      f32x4 zero4 = {0.f, 0.f, 0.f, 0.f};
      __asm__ volatile("" : "+v"(zero4));

      int tile = blockIdx.x;
#pragma unroll 1
      while (tile < ntl) {
        const int nodeBase = tile * NPB;
        if (tid < 256) {
          int node = nodeBase + (tid >> 4);
          srcL[tid] = ((node < Mloc) ? p.src[nodeBase * 16 + tid] : 0) << 10;
        }
        if (tid == 0) *nextTp = (int)gridDim.x + atomicAdd(ctr, 1);
        float c_st[4] = {0.f, 0.f, 0.f, 0.f};
        BAR_LGKM();  // srcL + nextT visible; prev tile's LDS reads done
        const int my_next = *nextTp;

        {
          int s0A = srcL[r0row * 16 + 0], s0B = srcL[r1row * 16 + 0];
          __builtin_amdgcn_global_load_lds(
              (const __attribute__((address_space(1))) unsigned int*)(Pbase + s0A),
              (__attribute__((address_space(3))) unsigned int*)(Pb + r0row * PSTR), 16, 0, 0);
          __builtin_amdgcn_global_load_lds(
              (const __attribute__((address_space(1))) unsigned int*)(Pbase + s0B),
              (__attribute__((address_space(3))) unsigned int*)(Pb + r1row * PSTR), 16, 0, 0);
          int s1A = srcL[r0row * 16 + 1], s1B = srcL[r1row * 16 + 1];
          __builtin_amdgcn_global_load_lds(
              (const __attribute__((address_space(1))) unsigned int*)(Pbase + s1A),
              (__attribute__((address_space(3))) unsigned int*)(Pb + NPB * PSTR + r0row * PSTR), 16, 0, 0);
          __builtin_amdgcn_global_load_lds(
              (const __attribute__((address_space(1))) unsigned int*)(Pbase + s1B),
              (__attribute__((address_space(3))) unsigned int*)(Pb + NPB * PSTR + r1row * PSTR), 16, 0, 0);
        }
        int sA = srcL[r0row * 16 + 2], sB = srcL[r1row * 16 + 2];

        int pc = 0, pg = 2;
#pragma unroll 1
        for (int t = 0; t < 16; ++t) {
          short* Pc = Pb + pc * NPB * PSTR;
          short* Pg = Pb + pg * NPB * PSTR;
          const short* Hp = Hb + ((t + 1) & 1) * NPB * HSTR;
          short* Hw = Hb + (t & 1) * NPB * HSTR;
          pc = (pc == 2) ? 0 : pc + 1;
          pg = (pg == 2) ? 0 : pg + 1;

          STEP_BAR2();  // gather(t) landed; gather(t+1) stays in flight

          const short* pB = Pc + nn * PSTR + wave * 16 + (quad & 1) * 8;
          short8 pf0 = *(const short8*)(pB + 0 * 128);
          short8 pf1 = *(const short8*)(pB + 1 * 128);
          short8 pf2 = *(const short8*)(pB + 2 * 128);
          short8 pf3 = *(const short8*)(pB + 3 * 128);

          __builtin_amdgcn_global_load_lds(
              (const __attribute__((address_space(1))) unsigned int*)(Pbase + sA),
              (__attribute__((address_space(3))) unsigned int*)(Pg + r0row * PSTR), 16, 0, 0);
          __builtin_amdgcn_global_load_lds(
              (const __attribute__((address_space(1))) unsigned int*)(Pbase + sB),
              (__attribute__((address_space(3))) unsigned int*)(Pg + r1row * PSTR), 16, 0, 0);
          {
            int tn = (t + 3 < 16) ? t + 3 : 15;
            sA = srcL[r0row * 16 + tn];
            sB = srcL[r1row * 16 + tn];
          }

          f32x4 acc[4];
          acc[0] = __builtin_amdgcn_mfma_f32_16x16x32_bf16(ident, pf0, zero4, 0, 0, 0);
          acc[1] = __builtin_amdgcn_mfma_f32_16x16x32_bf16(ident, pf1, zero4, 0, 0, 0);
          acc[2] = __builtin_amdgcn_mfma_f32_16x16x32_bf16(ident, pf2, zero4, 0, 0, 0);
          acc[3] = __builtin_amdgcn_mfma_f32_16x16x32_bf16(ident, pf3, zero4, 0, 0, 0);

          if (t) {
#pragma unroll
            for (int kt = 0; kt < 4; ++kt) {
              short8 hb = *(const short8*)(Hp + nn * HSTR + kt * 32 + quad * 8);
#pragma unroll
              for (int q = 0; q < 4; ++q)
                acc[q] = __builtin_amdgcn_mfma_f32_16x16x32_bf16(wreg[kt][q], hb, acc[q], 0, 0, 0);
            }
          }

          float hv[4];
#pragma unroll
          for (int r = 0; r < 4; ++r)
            hv[r] = lstm_elem(acc[0][r], acc[1][r], acc[2][r], acc[3][r], c_st[r]);
          uint2 pk;
          pk.x = pack_bf2(hv[0], hv[1]);
          pk.y = pack_bf2(hv[2], hv[3]);
          *(uint2*)(Hw + nn * HSTR + wave * 16 + quad * 4) = pk;
        }

        BAR_LGKM();  // h(15) visible (buf1)

        if (FO == 128 || wave < 4) {
          const short* Hf = Hb + NPB * HSTR;
          const int cbase = wave * 16;
          f32x4 accO;
#pragma unroll
          for (int r = 0; r < 4; ++r) accO[r] = blw[cbase + quad * 4 + r];
#pragma unroll
          for (int kt = 0; kt < 4; ++kt) {
            short8 wlA = *(const short8*)(Wlw + (size_t)(cbase + nn) * HID + kt * 32 + quad * 8);
            short8 hb = *(const short8*)(Hf + nn * HSTR + kt * 32 + quad * 8);
            accO = __builtin_amdgcn_mfma_f32_16x16x32_bf16(wlA, hb, accO, 0, 0, 0);
            short8 wrA = *(const short8*)(Wrw + (size_t)(cbase + nn) * HID + kt * 32 + quad * 8);
            short8 cb = *(const short8*)(cur + (size_t)(nodeBase + nn) * HID + kt * 32 + quad * 8);
            accO = __builtin_amdgcn_mfma_f32_16x16x32_bf16(wrA, cb, accO, 0, 0, 0);
          }
          if (l < 2) {
#pragma unroll
            for (int r = 0; r < 4; ++r) accO[r] = fmaxf(accO[r], 0.0f);
          }
          int node = nodeBase + nn;
          if (node < Mloc) {
            if (l == 2) {
              *(f32x4*)(p.outF + (size_t)node * 64 + cbase + quad * 4) = accO;
            } else {
              uint2 pko;
              pko.x = pack_bf2(accO[0], accO[1]);
              pko.y = pack_bf2(accO[2], accO[3]);
              *(uint2*)(nxt + (size_t)node * 128 + cbase + quad * 4) = pko;
            }
          }
        }
        tile = my_next;
      }
    }
    if (l < 2) {
      grid.sync();
      short* t = cur; cur = nxt; nxt = t;
    }
  }
}

// =================== fallback path (R10, used only if coop launch fails) =====
__global__ void conv_x_kernel(const float* __restrict__ x, short* __restrict__ xb, int n,
                              int* __restrict__ tctr) {
  int i = blockIdx.x * blockDim.x + threadIdx.x;
  if (i < 8) tctr[i] = 0;
  int stride = gridDim.x * blockDim.x;
  for (; i < n; i += stride) xb[i] = f2bf(x[i]);
}

__global__ void conv_layer_kernel(const float* __restrict__ Wih, const float* __restrict__ Whh,
                                  const float* __restrict__ bih, const float* __restrict__ bhh,
                                  const float* __restrict__ Wl, const float* __restrict__ Wr, int foK,
                                  short* __restrict__ wihB, short* __restrict__ whhB,
                                  short* __restrict__ wlB, short* __restrict__ wrB,
                                  float* __restrict__ bsum) {
  int i = blockIdx.x * blockDim.x + threadIdx.x;
  if (i < 512 * HID) {
    float sc = ((i >> 14) == 2) ? PK2 : NK1;
    wihB[i] = f2bf(Wih[i] * sc);
    whhB[i] = f2bf(Whh[i] * sc);
  }
  if (i < foK) { wlB[i] = f2bf(Wl[i]); wrB[i] = f2bf(Wr[i]); }
  if (i < 512) bsum[i] = (bih[i] + bhh[i]) * (((i >> 7) == 2) ? PK2 : NK1);
}

__global__ __launch_bounds__(512, 4) void pgemm_kernel(
    const short* __restrict__ A, const short* __restrict__ W,
    const float* __restrict__ bias, short* __restrict__ out, int M, int ntiles) {
  __shared__ short ldsA[32 * ASTR];
  const int tid = threadIdx.x;
  const int wave = tid >> 6, lane = tid & 63;
  const int quad = lane >> 4, nn = lane & 15;
  const int cbase = wave * 64;
  short8 wreg[4][4];
#pragma unroll
  for (int kt = 0; kt < 4; ++kt)
#pragma unroll
    for (int nt = 0; nt < 4; ++nt)
      wreg[kt][nt] = *(const short8*)(W + (size_t)(cbase + nt * 16 + nn) * HID + kt * 32 + quad * 8);
  f32x4 bias4[4];
#pragma unroll
  for (int nt = 0; nt < 4; ++nt)
#pragma unroll
    for (int r = 0; r < 4; ++r) bias4[nt][r] = bias[cbase + nt * 16 + quad * 4 + r];
  const int srow = wave * 4 + quad;
  const int scol = nn * 8;
  int rt = blockIdx.x;
  short8 avn;
  {
    int r = rt * 32 + srow;
    if (r > M - 1) r = M - 1;
    avn = *(const short8*)(A + (size_t)r * HID + scol);
  }
#pragma unroll 1
  for (; rt < ntiles; rt += gridDim.x) {
    const int row0 = rt * 32;
    BAR_LGKM();
    *(short8*)(ldsA + srow * ASTR + scol) = avn;
    {
      int rn = rt + gridDim.x;
      if (rn < ntiles) {
        int r = rn * 32 + srow;
        if (r > M - 1) r = M - 1;
        avn = *(const short8*)(A + (size_t)r * HID + scol);
      }
    }
    BAR_LGKM();
    f32x4 acc[2][4];
#pragma unroll
    for (int b = 0; b < 2; ++b)
#pragma unroll
      for (int nt = 0; nt < 4; ++nt) acc[b][nt] = bias4[nt];
#pragma unroll
    for (int kt = 0; kt < 4; ++kt) {
      short8 af0 = *(const short8*)(ldsA + nn * ASTR + kt * 32 + quad * 8);
      short8 af1 = *(const short8*)(ldsA + (16 + nn) * ASTR + kt * 32 + quad * 8);
#pragma unroll
      for (int nt = 0; nt < 4; ++nt) {
        acc[0][nt] = __builtin_amdgcn_mfma_f32_16x16x32_bf16(wreg[kt][nt], af0, acc[0][nt], 0, 0, 0);
        acc[1][nt] = __builtin_amdgcn_mfma_f32_16x16x32_bf16(wreg[kt][nt], af1, acc[1][nt], 0, 0, 0);
      }
    }
#pragma unroll
    for (int b = 0; b < 2; ++b) {
      int row = row0 + b * 16 + nn;
      if (row < M) {
#pragma unroll
        for (int nt = 0; nt < 4; ++nt) {
          uint2 pk;
          pk.x = pack_bf2(acc[b][nt][0], acc[b][nt][1]);
          pk.y = pack_bf2(acc[b][nt][2], acc[b][nt][3]);
          *(uint2*)(out + (size_t)row * 512 + cbase + nt * 16 + quad * 4) = pk;
        }
      }
    }
  }
}

template <int FO, bool RELU, bool OUTF32>
__global__ __launch_bounds__(512, 4) void lstm_fused_kernel(
    const short* __restrict__ P, const short* __restrict__ Whh,
    const int* __restrict__ src, const short* __restrict__ cur,
    const short* __restrict__ Wl, const short* __restrict__ Wr,
    const float* __restrict__ bl,
    short* __restrict__ outB, float* __restrict__ outF, int M, int ntiles,
    int* __restrict__ tctr) {
  extern __shared__ char smem[];
  short* Pb = (short*)smem;
  short* Hb = Pb + 3 * NPB * PSTR;
  int* srcL = (int*)(Hb + 2 * NPB * HSTR);
  int* nextTp = srcL + 256;
  const int tid = threadIdx.x;
  const int wave = tid >> 6, lane = tid & 63;
  const int quad = lane >> 4, nn = lane & 15;
  const int r0row = wave * 2, r1row = wave * 2 + 1;
  const char* Pbase = (const char*)P + lane * 16;
  short8 wreg[4][4];
#pragma unroll
  for (int kt = 0; kt < 4; ++kt)
#pragma unroll
    for (int q = 0; q < 4; ++q)
      wreg[kt][q] = *(const short8*)(Whh + (size_t)(q * 128 + wave * 16 + nn) * HID + kt * 32 + quad * 8);
  short8 ident;
#pragma unroll
  for (int e = 0; e < 8; ++e) ident[e] = (short)((quad * 8 + e == nn) ? 0x3F80 : 0);
  f32x4 zero4 = {0.f, 0.f, 0.f, 0.f};
  __asm__ volatile("" : "+v"(zero4));
  int tile = blockIdx.x;
  while (tile < ntiles) {
    const int nodeBase = tile * NPB;
    if (tid < 256) {
      int node = nodeBase + (tid >> 4);
      srcL[tid] = ((node < M) ? src[nodeBase * 16 + tid] : 0) << 10;
    }
    if (tid == 0) *nextTp = (int)gridDim.x + atomicAdd(tctr, 1);
    float c_st[4] = {0.f, 0.f, 0.f, 0.f};
    BAR_LGKM();
    const int my_next = *nextTp;
    {
      int s0A = srcL[r0row * 16 + 0], s0B = srcL[r1row * 16 + 0];
      __builtin_amdgcn_global_load_lds(
          (const __attribute__((address_space(1))) unsigned int*)(Pbase + s0A),
          (__attribute__((address_space(3))) unsigned int*)(Pb + r0row * PSTR), 16, 0, 0);
      __builtin_amdgcn_global_load_lds(
          (const __attribute__((address_space(1))) unsigned int*)(Pbase + s0B),
          (__attribute__((address_space(3))) unsigned int*)(Pb + r1row * PSTR), 16, 0, 0);
      int s1A = srcL[r0row * 16 + 1], s1B = srcL[r1row * 16 + 1];
      __builtin_amdgcn_global_load_lds(
          (const __attribute__((address_space(1))) unsigned int*)(Pbase + s1A),
          (__attribute__((address_space(3))) unsigned int*)(Pb + NPB * PSTR + r0row * PSTR), 16, 0, 0);
      __builtin_amdgcn_global_load_lds(
          (const __attribute__((address_space(1))) unsigned int*)(Pbase + s1B),
          (__attribute__((address_space(3))) unsigned int*)(Pb + NPB * PSTR + r1row * PSTR), 16, 0, 0);
    }
    int sA = srcL[r0row * 16 + 2], sB = srcL[r1row * 16 + 2];
    int pc = 0, pg = 2;
#pragma unroll 1
    for (int t = 0; t < 16; ++t) {
      short* Pc = Pb + pc * NPB * PSTR;
      short* Pg = Pb + pg * NPB * PSTR;
      const short* Hp = Hb + ((t + 1) & 1) * NPB * HSTR;
      short* Hw = Hb + (t & 1) * NPB * HSTR;
      pc = (pc == 2) ? 0 : pc + 1;
      pg = (pg == 2) ? 0 : pg + 1;
      STEP_BAR2();
      const short* pB = Pc + nn * PSTR + wave * 16 + (quad & 1) * 8;
      short8 pf0 = *(const short8*)(pB + 0 * 128);
      short8 pf1 = *(const short8*)(pB + 1 * 128);
      short8 pf2 = *(const short8*)(pB + 2 * 128);
      short8 pf3 = *(const short8*)(pB + 3 * 128);
      __builtin_amdgcn_global_load_lds(
          (const __attribute__((address_space(1))) unsigned int*)(Pbase + sA),
          (__attribute__((address_space(3))) unsigned int*)(Pg + r0row * PSTR), 16, 0, 0);
      __builtin_amdgcn_global_load_lds(
          (const __attribute__((address_space(1))) unsigned int*)(Pbase + sB),
          (__attribute__((address_space(3))) unsigned int*)(Pg + r1row * PSTR), 16, 0, 0);
      {
        int tn = (t + 3 < 16) ? t + 3 : 15;
        sA = srcL[r0row * 16 + tn];
        sB = srcL[r1row * 16 + tn];
      }
      f32x4 acc[4];
      acc[0] = __builtin_amdgcn_mfma_f32_16x16x32_bf16(ident, pf0, zero4, 0, 0, 0);
      acc[1] = __builtin_amdgcn_mfma_f32_16x16x32_bf16(ident, pf1, zero4, 0, 0, 0);
      acc[2] = __builtin_amdgcn_mfma_f32_16x16x32_bf16(ident, pf2, zero4, 0, 0, 0);
      acc[3] = __builtin_amdgcn_mfma_f32_16x16x32_bf16(ident, pf3, zero4, 0, 0, 0);
      if (t) {
#pragma unroll
        for (int kt = 0; kt < 4; ++kt) {
          short8 hb = *(const short8*)(Hp + nn * HSTR + kt * 32 + quad * 8);
#pragma unroll
          for (int q = 0; q < 4; ++q)
            acc[q] = __builtin_amdgcn_mfma_f32_16x16x32_bf16(wreg[kt][q], hb, acc[q], 0, 0, 0);
        }
      }
      float hv[4];
#pragma unroll
      for (int r = 0; r < 4; ++r)
        hv[r] = lstm_elem(acc[0][r], acc[1][r], acc[2][r], acc[3][r], c_st[r]);
      uint2 pk;
      pk.x = pack_bf2(hv[0], hv[1]);
      pk.y = pack_bf2(hv[2], hv[3]);
      *(uint2*)(Hw + nn * HSTR + wave * 16 + quad * 4) = pk;
    }
    BAR_LGKM();
    if (FO == 128 || wave < 4) {
      const short* Hf = Hb + NPB * HSTR;
      const int cbase = wave * 16;
      f32x4 accO;
#pragma unroll
      for (int r = 0; r < 4; ++r) accO[r] = bl[cbase + quad * 4 + r];
#pragma unroll
      for (int kt = 0; kt < 4; ++kt) {
        short8 wlA = *(const short8*)(Wl + (size_t)(cbase + nn) * HID + kt * 32 + quad * 8);
        short8 hb = *(const short8*)(Hf + nn * HSTR + kt * 32 + quad * 8);
        accO = __builtin_amdgcn_mfma_f32_16x16x32_bf16(wlA, hb, accO, 0, 0, 0);
        short8 wrA = *(const short8*)(Wr + (size_t)(cbase + nn) * HID + kt * 32 + quad * 8);
        short8 cb = *(const short8*)(cur + (size_t)(nodeBase + nn) * HID + kt * 32 + quad * 8);
        accO = __builtin_amdgcn_mfma_f32_16x16x32_bf16(wrA, cb, accO, 0, 0, 0);
      }
      if (RELU) {
#pragma unroll
        for (int r = 0; r < 4; ++r) accO[r] = fmaxf(accO[r], 0.0f);
      }
      int node = nodeBase + nn;
      if (node < M) {
        if (OUTF32) {
          *(f32x4*)(outF + (size_t)node * FO + cbase + quad * 4) = accO;
        } else {
          uint2 pko;
          pko.x = pack_bf2(accO[0], accO[1]);
          pko.y = pack_bf2(accO[2], accO[3]);
          *(uint2*)(outB + (size_t)node * FO + cbase + quad * 4) = pko;
        }
      }
    }
    tile = my_next;
  }
}

// ---------------- launcher ----------------
extern "C" void kernel_launch(void* const* d_in, const int* in_sizes, int n_in,
                              void* d_out, int out_size, void* d_ws, size_t ws_size,
                              hipStream_t stream) {
  const float* x = (const float*)d_in[0];
  const int* src = (const int*)d_in[1];
  const float* Wih[3] = {(const float*)d_in[2], (const float*)d_in[9], (const float*)d_in[16]};
  const float* Whh[3] = {(const float*)d_in[3], (const float*)d_in[10], (const float*)d_in[17]};
  const float* bih[3] = {(const float*)d_in[4], (const float*)d_in[11], (const float*)d_in[18]};
  const float* bhh[3] = {(const float*)d_in[5], (const float*)d_in[12], (const float*)d_in[19]};
  const float* Wl[3]  = {(const float*)d_in[6], (const float*)d_in[13], (const float*)d_in[20]};
  const float* bl[3]  = {(const float*)d_in[7], (const float*)d_in[14], (const float*)d_in[21]};
  const float* Wr[3]  = {(const float*)d_in[8], (const float*)d_in[15], (const float*)d_in[22]};

  const int M = in_sizes[0] / HID;  // 50000

  char* ws = (char*)d_ws;
  size_t off = 0;
  auto alloc = [&](size_t bytes) -> void* {
    void* p = ws + off;
    off += (bytes + 255) & ~(size_t)255;
    return p;
  };
  short* curA = (short*)alloc((size_t)M * HID * 2);
  short* curB = (short*)alloc((size_t)M * HID * 2);
  short* Pbuf = (short*)alloc((size_t)M * 512 * 2);
  short* wihB[3]; short* whhB[3]; short* wlB[3]; short* wrB[3]; float* bsum[3];
  for (int l = 0; l < 3; ++l) {
    wihB[l] = (short*)alloc(512 * HID * 2);
    whhB[l] = (short*)alloc(512 * HID * 2);
    wlB[l]  = (short*)alloc(HID * HID * 2);
    wrB[l]  = (short*)alloc(HID * HID * 2);
    bsum[l] = (float*)alloc(512 * 4);
  }
  int* tctr = (int*)alloc(256);

  const int nltiles = (M + NPB - 1) / NPB;  // 3125
  const int ntiles = (M + 31) / 32;         // 1563

  (void)hipFuncSetAttribute((const void*)fused_all,
                            hipFuncAttributeMaxDynamicSharedMemorySize, LSTM_LDS_BYTES);

  // cooperative grid: exactly the co-resident capacity
  int dev = 0;
  (void)hipGetDevice(&dev);
  int ncu = 256;
  (void)hipDeviceGetAttribute(&ncu, hipDeviceAttributeMultiprocessorCount, dev);
  int occB = 0;
  (void)hipOccupancyMaxActiveBlocksPerMultiprocessor(&occB, (const void*)fused_all, 512,
                                                     LSTM_LDS_BYTES);
  if (occB < 1) occB = 1;
  long grid = (long)occB * (long)ncu;
  if (grid > 512) grid = 512;

  KParams kp;
  kp.x = x; kp.src = src;
  for (int l = 0; l < 3; ++l) {
    kp.Wih[l] = Wih[l]; kp.Whh[l] = Whh[l];
    kp.bih[l] = bih[l]; kp.bhh[l] = bhh[l];
    kp.Wl[l] = Wl[l]; kp.bl[l] = bl[l]; kp.Wr[l] = Wr[l];
    kp.wihB[l] = wihB[l]; kp.whhB[l] = whhB[l];
    kp.wlB[l] = wlB[l]; kp.wrB[l] = wrB[l];
    kp.bsum[l] = bsum[l];
  }
  kp.curA = curA; kp.curB = curB; kp.Pbuf = Pbuf;
  kp.tctr = tctr; kp.outF = (float*)d_out;
  kp.M = M; kp.ntiles = ntiles; kp.nltiles = nltiles;

  void* kargs[] = {(void*)&kp};
  hipError_t le = hipLaunchCooperativeKernel((const void*)fused_all, dim3((unsigned)grid),
                                             dim3(512), kargs, (unsigned)LSTM_LDS_BYTES, stream);
  if (le != hipSuccess) {
    // ---------------- fallback: proven 7-kernel path (R10) ----------------
    (void)hipFuncSetAttribute((const void*)lstm_fused_kernel<128, true, false>,
                              hipFuncAttributeMaxDynamicSharedMemorySize, LSTM_LDS_BYTES);
    (void)hipFuncSetAttribute((const void*)lstm_fused_kernel<64, false, true>,
                              hipFuncAttributeMaxDynamicSharedMemorySize, LSTM_LDS_BYTES);
    conv_x_kernel<<<2048, 256, 0, stream>>>(x, curA, M * HID, tctr);
    for (int l = 0; l < 3; ++l) {
      const int Fo = (l == 2) ? 64 : 128;
      conv_layer_kernel<<<256, 256, 0, stream>>>(Wih[l], Whh[l], bih[l], bhh[l], Wl[l], Wr[l],
                                                 Fo * HID, wihB[l], whhB[l], wlB[l], wrB[l], bsum[l]);
    }
    short* cur = curA;
    short* nxt = curB;
    for (int l = 0; l < 3; ++l) {
      pgemm_kernel<<<784, 512, 0, stream>>>(cur, wihB[l], bsum[l], Pbuf, M, ntiles);
      if (l < 2) {
        lstm_fused_kernel<128, true, false><<<512, 512, LSTM_LDS_BYTES, stream>>>(
            Pbuf, whhB[l], src, cur, wlB[l], wrB[l], bl[l], nxt, nullptr, M, nltiles, tctr + l);
        short* tswap = cur; cur = nxt; nxt = tswap;
      } else {
        lstm_fused_kernel<64, false, true><<<512, 512, LSTM_LDS_BYTES, stream>>>(
            Pbuf, whhB[l], src, cur, wlB[l], wrB[l], bl[l], nullptr, (float*)d_out, M, nltiles,
            tctr + 2);
      }
    }
  }
}

// Round 12
// 703.894 us; speedup vs baseline: 1.6980x; 1.6980x over previous
//
#include <hip/hip_runtime.h>
#include <cstddef>
#include <cstdint>

typedef __attribute__((ext_vector_type(4))) float f32x4;
typedef __attribute__((ext_vector_type(8))) short short8;

#define HID 128
#define NK1 -1.4426950408889634f  // -log2(e)
#define PK2 2.8853900817779268f   // +2*log2(e)

// LDS-only barrier: no vmcnt(0) drain.
#define BAR_LGKM() __asm__ volatile("s_waitcnt lgkmcnt(0)\ns_barrier" ::: "memory")
// depth-2 prefetch fence: retire gather(t), keep gather(t+1) in flight
#define STEP_BAR2() __asm__ volatile("s_waitcnt vmcnt(2) lgkmcnt(0)\ns_barrier" ::: "memory")
// staging fence: A-tile load/ds_write visible to all waves
#define BAR_VM_LGKM() __asm__ volatile("s_waitcnt vmcnt(0) lgkmcnt(0)\ns_barrier" ::: "memory")

__device__ __forceinline__ short f2bf(float f) {
  unsigned u = __builtin_bit_cast(unsigned, f);
  u += 0x7FFFu + ((u >> 16) & 1u);
  return (short)(u >> 16);
}
__device__ __forceinline__ unsigned pack_bf2(float a, float b) {
  unsigned ua = __builtin_bit_cast(unsigned, a) + 0x8000u;
  unsigned ub = __builtin_bit_cast(unsigned, b) + 0x8000u;
  return __builtin_amdgcn_perm(ub, ua, 0x07060302u);
}

// folded LSTM cell: inputs are PRE-SCALED pre-activations
// si,sf,so = -log2e*(gate), sg = 2log2e*(g). 5 exp2 + 2 rcp (algebraic min).
__device__ __forceinline__ float lstm_elem(float si, float sf, float sg, float so, float& c) {
  float Ei = __builtin_amdgcn_exp2f(si);
  float Ef = __builtin_amdgcn_exp2f(sf);
  float Tg = __builtin_amdgcn_exp2f(sg);
  float Eo = __builtin_amdgcn_exp2f(so);
  float u = 1.0f + Ei, w = 1.0f + Ef, v = Tg + 1.0f, Tm = Tg - 1.0f;
  float t0 = u * v;
  float num = __builtin_fmaf(c, t0, w * Tm);
  float cn = num * __builtin_amdgcn_rcpf(w * t0);
  c = cn;
  float Tc = __builtin_amdgcn_exp2f(PK2 * cn);
  return (Tc - 1.0f) * __builtin_amdgcn_rcpf((1.0f + Eo) * (Tc + 1.0f));
}

// ---------------- ONE merged conversion kernel (replaces 4 dispatches) -------
struct ConvParams {
  const float* x; short* xb; int n;
  const float* Wih[3]; const float* Whh[3];
  const float* bih[3]; const float* bhh[3];
  const float* Wl[3];  const float* Wr[3];
  short* wihB[3]; short* whhB[3]; short* wlB[3]; short* wrB[3];
  float* bsum[3];
  int foK[3];
  int* tctr;
};

__global__ void conv_all_kernel(ConvParams p) {
  const int gi = blockIdx.x * blockDim.x + threadIdx.x;
  const int gs = gridDim.x * blockDim.x;
  if (gi < 8) p.tctr[gi] = 0;  // dynamic-tile counters (runs before all lstm dispatches)
  for (int i = gi; i < p.n; i += gs) p.xb[i] = f2bf(p.x[i]);
#pragma unroll 1
  for (int l = 0; l < 3; ++l) {
    if (gi < 512 * HID) {
      float sc = ((gi >> 14) == 2) ? PK2 : NK1;  // gate = row>>7 = i>>14
      p.wihB[l][gi] = f2bf(p.Wih[l][gi] * sc);
      p.whhB[l][gi] = f2bf(p.Whh[l][gi] * sc);
    }
    if (gi < p.foK[l]) {
      p.wlB[l][gi] = f2bf(p.Wl[l][gi]);
      p.wrB[l][gi] = f2bf(p.Wr[l][gi]);
    }
    if (gi < 512)
      p.bsum[l][gi] = (p.bih[l][gi] + p.bhh[l][gi]) * (((gi >> 7) == 2) ? PK2 : NK1);
  }
}

// ------- persistent P-GEMM: P = A @ Wih^T + bias -> bf16 [M,512] -------------
// R8-proven (v2): A-tile staged in LDS once per tile (vs 8x redundant VMEM),
// ldsO-coalesced output.
#define OSTR 524
#define ASTR 136
__global__ __launch_bounds__(512, 4) void pgemm_kernel(
    const short* __restrict__ A, const short* __restrict__ W,
    const float* __restrict__ bias, short* __restrict__ out, int M, int ntiles) {
  __shared__ short ldsA[32 * ASTR];  // 8.5 KB
  __shared__ short ldsO[32 * OSTR];  // 33.5 KB
  const int tid = threadIdx.x;
  const int wave = tid >> 6, lane = tid & 63;
  const int quad = lane >> 4, nn = lane & 15;
  const int cbase = wave * 64;

  short8 wreg[4][4];
#pragma unroll
  for (int kt = 0; kt < 4; ++kt)
#pragma unroll
    for (int nt = 0; nt < 4; ++nt)
      wreg[kt][nt] = *(const short8*)(W + (size_t)(cbase + nt * 16 + nn) * HID + kt * 32 + quad * 8);
  f32x4 bias4[4];
#pragma unroll
  for (int nt = 0; nt < 4; ++nt)
#pragma unroll
    for (int r = 0; r < 4; ++r) bias4[nt][r] = bias[cbase + nt * 16 + quad * 4 + r];

  // staging: lane covers row wave*4 + (lane>>4), cols (lane&15)*8 .. +8
  const int srow = wave * 4 + quad;
  const int scol = nn * 8;

#pragma unroll 1
  for (int rt = blockIdx.x; rt < ntiles; rt += gridDim.x) {
    const int row0 = rt * 32;
    {
      int r = row0 + srow;
      if (r > M - 1) r = M - 1;
      short8 av = *(const short8*)(A + (size_t)r * HID + scol);
      *(short8*)(ldsA + srow * ASTR + scol) = av;
    }
    BAR_VM_LGKM();  // A tile visible to all waves

    f32x4 acc[2][4];
#pragma unroll
    for (int b = 0; b < 2; ++b)
#pragma unroll
      for (int nt = 0; nt < 4; ++nt) acc[b][nt] = bias4[nt];
#pragma unroll
    for (int kt = 0; kt < 4; ++kt) {
      short8 af0 = *(const short8*)(ldsA + nn * ASTR + kt * 32 + quad * 8);
      short8 af1 = *(const short8*)(ldsA + (16 + nn) * ASTR + kt * 32 + quad * 8);
#pragma unroll
      for (int nt = 0; nt < 4; ++nt) {
        acc[0][nt] = __builtin_amdgcn_mfma_f32_16x16x32_bf16(wreg[kt][nt], af0, acc[0][nt], 0, 0, 0);
        acc[1][nt] = __builtin_amdgcn_mfma_f32_16x16x32_bf16(wreg[kt][nt], af1, acc[1][nt], 0, 0, 0);
      }
    }
    BAR_LGKM();  // ldsA reads + previous iteration's ldsO reads complete
#pragma unroll
    for (int b = 0; b < 2; ++b)
#pragma unroll
      for (int nt = 0; nt < 4; ++nt) {
        uint2 pk;
        pk.x = pack_bf2(acc[b][nt][0], acc[b][nt][1]);
        pk.y = pack_bf2(acc[b][nt][2], acc[b][nt][3]);
        *(uint2*)(ldsO + (b * 16 + nn) * OSTR + cbase + nt * 16 + quad * 4) = pk;
      }
    BAR_LGKM();
#pragma unroll
    for (int idx = tid; idx < 32 * 64; idx += 512) {
      int row = idx >> 6, c8 = (idx & 63) * 8;
      if (row0 + row < M)
        *(short8*)(out + (size_t)(row0 + row) * 512 + c8) = *(const short8*)(ldsO + row * OSTR + c8);
    }
  }
}

// ------- persistent LSTM + FUSED output GEMM ---------------------------------
// v9 (R8, best measured 187.5 us): identity-A MFMA does the bf16->f32 P
//     conversion on the matrix pipe; depth-2 DMA gather; dynamic tiles.
//     BIT-IDENTICAL to R8. (R11's cooperative fusion refuted: grid.sync on
//     8 XCDs forces L2 writeback-invalidate -> +183MB writes, utils halved.)
#define NPB 16
#define PSTR 520
#define HSTR 152
#define LSTM_LDS_BYTES ((3 * NPB * PSTR + 2 * NPB * HSTR) * 2 + 256 * 4 + 16)  // 60688

template <int FO, bool RELU, bool OUTF32>
__global__ __launch_bounds__(512, 4) void lstm_fused_kernel(
    const short* __restrict__ P, const short* __restrict__ Whh,
    const int* __restrict__ src, const short* __restrict__ cur,
    const short* __restrict__ Wl, const short* __restrict__ Wr,
    const float* __restrict__ bl,
    short* __restrict__ outB, float* __restrict__ outF, int M, int ntiles,
    int* __restrict__ tctr) {
  extern __shared__ char smem[];
  short* Pb = (short*)smem;                 // [3][16][520]
  short* Hb = Pb + 3 * NPB * PSTR;          // [2][16][152]
  int* srcL = (int*)(Hb + 2 * NPB * HSTR);  // [256] byte offsets into P
  int* nextTp = srcL + 256;

  const int tid = threadIdx.x;
  const int wave = tid >> 6, lane = tid & 63;
  const int quad = lane >> 4, nn = lane & 15;
  const int r0row = wave * 2, r1row = wave * 2 + 1;
  const char* Pbase = (const char*)P + lane * 16;  // per-lane 16B column base

  // Whh fragments: for each gate q, rows [q*128 + wave*16, +16)  (64 VGPRs)
  short8 wreg[4][4];  // [kt][q]
#pragma unroll
  for (int kt = 0; kt < 4; ++kt)
#pragma unroll
    for (int q = 0; q < 4; ++q)
      wreg[kt][q] = *(const short8*)(Whh + (size_t)(q * 128 + wave * 16 + nn) * HID + kt * 32 + quad * 8);

  // identity A-fragment: A[row=nn][k=quad*8+e] = (quad*8+e==nn) ? 1.0bf16 : 0
  short8 ident;
#pragma unroll
  for (int e = 0; e < 8; ++e) ident[e] = (short)((quad * 8 + e == nn) ? 0x3F80 : 0);
  // persistent zero C-operand (kept materialized; avoids per-ts zero-fill)
  f32x4 zero4 = {0.f, 0.f, 0.f, 0.f};
  __asm__ volatile("" : "+v"(zero4));

  int tile = blockIdx.x;
  while (tile < ntiles) {
    const int nodeBase = tile * NPB;
    if (tid < 256) {
      int node = nodeBase + (tid >> 4);
      srcL[tid] = ((node < M) ? src[nodeBase * 16 + tid] : 0) << 10;  // byte offset (row*1024)
    }
    if (tid == 0) *nextTp = (int)gridDim.x + atomicAdd(tctr, 1);
    float c_st[4] = {0.f, 0.f, 0.f, 0.f};
    BAR_LGKM();  // srcL + nextT visible; prev tile's LDS reads done
    const int my_next = *nextTp;  // read post-barrier; next write is >16 barriers away

    // prologue: gather(0) -> buf0, gather(1) -> buf1
    {
      int s0A = srcL[r0row * 16 + 0], s0B = srcL[r1row * 16 + 0];
      __builtin_amdgcn_global_load_lds(
          (const __attribute__((address_space(1))) unsigned int*)(Pbase + s0A),
          (__attribute__((address_space(3))) unsigned int*)(Pb + r0row * PSTR), 16, 0, 0);
      __builtin_amdgcn_global_load_lds(
          (const __attribute__((address_space(1))) unsigned int*)(Pbase + s0B),
          (__attribute__((address_space(3))) unsigned int*)(Pb + r1row * PSTR), 16, 0, 0);
      int s1A = srcL[r0row * 16 + 1], s1B = srcL[r1row * 16 + 1];
      __builtin_amdgcn_global_load_lds(
          (const __attribute__((address_space(1))) unsigned int*)(Pbase + s1A),
          (__attribute__((address_space(3))) unsigned int*)(Pb + NPB * PSTR + r0row * PSTR), 16, 0, 0);
      __builtin_amdgcn_global_load_lds(
          (const __attribute__((address_space(1))) unsigned int*)(Pbase + s1B),
          (__attribute__((address_space(3))) unsigned int*)(Pb + NPB * PSTR + r1row * PSTR), 16, 0, 0);
    }
    int sA = srcL[r0row * 16 + 2], sB = srcL[r1row * 16 + 2];

    int pc = 0, pg = 2;  // buffer index of P(t) and of gather target (t+2)
#pragma unroll 1
    for (int t = 0; t < 16; ++t) {
      short* Pc = Pb + pc * NPB * PSTR;
      short* Pg = Pb + pg * NPB * PSTR;
      const short* Hp = Hb + ((t + 1) & 1) * NPB * HSTR;  // h(t-1)
      short* Hw = Hb + (t & 1) * NPB * HSTR;              // h(t)
      pc = (pc == 2) ? 0 : pc + 1;
      pg = (pg == 2) ? 0 : pg + 1;

      STEP_BAR2();  // gather(t) landed everywhere; gather(t+1) stays in flight

      // ---- read P B-fragments (b128; quads 2,3 mirror 0,1 -> A=0 lanes safe) ----
      const short* pB = Pc + nn * PSTR + wave * 16 + (quad & 1) * 8;
      short8 pf0 = *(const short8*)(pB + 0 * 128);
      short8 pf1 = *(const short8*)(pB + 1 * 128);
      short8 pf2 = *(const short8*)(pB + 2 * 128);
      short8 pf3 = *(const short8*)(pB + 3 * 128);

      // ---- issue gather(t+2) (clamped dummy at t>=14 keeps vmcnt uniform) ----
      __builtin_amdgcn_global_load_lds(
          (const __attribute__((address_space(1))) unsigned int*)(Pbase + sA),
          (__attribute__((address_space(3))) unsigned int*)(Pg + r0row * PSTR), 16, 0, 0);
      __builtin_amdgcn_global_load_lds(
          (const __attribute__((address_space(1))) unsigned int*)(Pbase + sB),
          (__attribute__((address_space(3))) unsigned int*)(Pg + r1row * PSTR), 16, 0, 0);
      {
        int tn = (t + 3 < 16) ? t + 3 : 15;
        sA = srcL[r0row * 16 + tn];
        sB = srcL[r1row * 16 + tn];
      }

      // ---- acc = I @ P  (matrix pipe does the bf16->f32 conversion) ----
      f32x4 acc[4];
      acc[0] = __builtin_amdgcn_mfma_f32_16x16x32_bf16(ident, pf0, zero4, 0, 0, 0);
      acc[1] = __builtin_amdgcn_mfma_f32_16x16x32_bf16(ident, pf1, zero4, 0, 0, 0);
      acc[2] = __builtin_amdgcn_mfma_f32_16x16x32_bf16(ident, pf2, zero4, 0, 0, 0);
      acc[3] = __builtin_amdgcn_mfma_f32_16x16x32_bf16(ident, pf3, zero4, 0, 0, 0);

      // ---- acc += Whh_rows @ h(t-1)^T ----
      if (t) {
#pragma unroll
        for (int kt = 0; kt < 4; ++kt) {
          short8 hb = *(const short8*)(Hp + nn * HSTR + kt * 32 + quad * 8);
#pragma unroll
          for (int q = 0; q < 4; ++q)
            acc[q] = __builtin_amdgcn_mfma_f32_16x16x32_bf16(wreg[kt][q], hb, acc[q], 0, 0, 0);
        }
      }

      // ---- cell: pure register math, write h(t) ----
      float hv[4];
#pragma unroll
      for (int r = 0; r < 4; ++r)
        hv[r] = lstm_elem(acc[0][r], acc[1][r], acc[2][r], acc[3][r], c_st[r]);
      uint2 pk;
      pk.x = pack_bf2(hv[0], hv[1]);
      pk.y = pack_bf2(hv[2], hv[3]);
      *(uint2*)(Hw + nn * HSTR + wave * 16 + quad * 4) = pk;
    }

    BAR_LGKM();  // h(15) visible (buf1)

    // ---- FUSED output: out[node] = h15@Wl^T + bl + cur@Wr^T ----
    // weights/bias loaded from global HERE (once per tile) to stay out of the
    // persistent register budget (occupancy: 2 blocks/CU at ~128 regs).
    if (FO == 128 || wave < 4) {
      const short* Hf = Hb + NPB * HSTR;
      const int cbase = wave * 16;
      f32x4 accO;
#pragma unroll
      for (int r = 0; r < 4; ++r) accO[r] = bl[cbase + quad * 4 + r];
#pragma unroll
      for (int kt = 0; kt < 4; ++kt) {
        short8 wlA = *(const short8*)(Wl + (size_t)(cbase + nn) * HID + kt * 32 + quad * 8);
        short8 hb = *(const short8*)(Hf + nn * HSTR + kt * 32 + quad * 8);
        accO = __builtin_amdgcn_mfma_f32_16x16x32_bf16(wlA, hb, accO, 0, 0, 0);
        short8 wrA = *(const short8*)(Wr + (size_t)(cbase + nn) * HID + kt * 32 + quad * 8);
        short8 cb = *(const short8*)(cur + (size_t)(nodeBase + nn) * HID + kt * 32 + quad * 8);
        accO = __builtin_amdgcn_mfma_f32_16x16x32_bf16(wrA, cb, accO, 0, 0, 0);
      }
      if (RELU) {
#pragma unroll
        for (int r = 0; r < 4; ++r) accO[r] = fmaxf(accO[r], 0.0f);
      }
      int node = nodeBase + nn;
      if (node < M) {
        if (OUTF32) {
          *(f32x4*)(outF + (size_t)node * FO + cbase + quad * 4) = accO;
        } else {
          uint2 pko;
          pko.x = pack_bf2(accO[0], accO[1]);
          pko.y = pack_bf2(accO[2], accO[3]);
          *(uint2*)(outB + (size_t)node * FO + cbase + quad * 4) = pko;
        }
      }
    }
    tile = my_next;
  }
}

// ---------------- launcher ----------------
extern "C" void kernel_launch(void* const* d_in, const int* in_sizes, int n_in,
                              void* d_out, int out_size, void* d_ws, size_t ws_size,
                              hipStream_t stream) {
  const float* x = (const float*)d_in[0];
  const int* src = (const int*)d_in[1];
  const float* Wih[3] = {(const float*)d_in[2], (const float*)d_in[9], (const float*)d_in[16]};
  const float* Whh[3] = {(const float*)d_in[3], (const float*)d_in[10], (const float*)d_in[17]};
  const float* bih[3] = {(const float*)d_in[4], (const float*)d_in[11], (const float*)d_in[18]};
  const float* bhh[3] = {(const float*)d_in[5], (const float*)d_in[12], (const float*)d_in[19]};
  const float* Wl[3]  = {(const float*)d_in[6], (const float*)d_in[13], (const float*)d_in[20]};
  const float* bl[3]  = {(const float*)d_in[7], (const float*)d_in[14], (const float*)d_in[21]};
  const float* Wr[3]  = {(const float*)d_in[8], (const float*)d_in[15], (const float*)d_in[22]};

  const int M = in_sizes[0] / HID;  // 50000

  char* ws = (char*)d_ws;
  size_t off = 0;
  auto alloc = [&](size_t bytes) -> void* {
    void* p = ws + off;
    off += (bytes + 255) & ~(size_t)255;
    return p;
  };
  short* curA = (short*)alloc((size_t)M * HID * 2);
  short* curB = (short*)alloc((size_t)M * HID * 2);
  short* Pbuf = (short*)alloc((size_t)M * 512 * 2);
  short* wihB[3]; short* whhB[3]; short* wlB[3]; short* wrB[3]; float* bsum[3];
  for (int l = 0; l < 3; ++l) {
    wihB[l] = (short*)alloc(512 * HID * 2);
    whhB[l] = (short*)alloc(512 * HID * 2);
    wlB[l]  = (short*)alloc(HID * HID * 2);
    wrB[l]  = (short*)alloc(HID * HID * 2);
    bsum[l] = (float*)alloc(512 * 4);
  }
  int* tctr = (int*)alloc(256);  // dynamic-tile counters (zeroed by conv_all_kernel)

  const int nltiles = (M + NPB - 1) / NPB;  // 3125
  const int ntiles = (M + 31) / 32;         // 1563

  (void)hipFuncSetAttribute((const void*)lstm_fused_kernel<128, true, false>,
                            hipFuncAttributeMaxDynamicSharedMemorySize, LSTM_LDS_BYTES);
  (void)hipFuncSetAttribute((const void*)lstm_fused_kernel<64, false, true>,
                            hipFuncAttributeMaxDynamicSharedMemorySize, LSTM_LDS_BYTES);

  ConvParams cp;
  cp.x = x; cp.xb = curA; cp.n = M * HID; cp.tctr = tctr;
  for (int l = 0; l < 3; ++l) {
    cp.Wih[l] = Wih[l]; cp.Whh[l] = Whh[l];
    cp.bih[l] = bih[l]; cp.bhh[l] = bhh[l];
    cp.Wl[l] = Wl[l];   cp.Wr[l] = Wr[l];
    cp.wihB[l] = wihB[l]; cp.whhB[l] = whhB[l];
    cp.wlB[l] = wlB[l];   cp.wrB[l] = wrB[l];
    cp.bsum[l] = bsum[l];
    cp.foK[l] = ((l == 2) ? 64 : 128) * HID;
  }
  conv_all_kernel<<<2048, 256, 0, stream>>>(cp);

  short* cur = curA;
  short* nxt = curB;
  for (int l = 0; l < 3; ++l) {
    pgemm_kernel<<<784, 512, 0, stream>>>(cur, wihB[l], bsum[l], Pbuf, M, ntiles);
    if (l < 2) {
      lstm_fused_kernel<128, true, false><<<512, 512, LSTM_LDS_BYTES, stream>>>(
          Pbuf, whhB[l], src, cur, wlB[l], wrB[l], bl[l], nxt, nullptr, M, nltiles, tctr + l);
      short* tswap = cur; cur = nxt; nxt = tswap;
    } else {
      lstm_fused_kernel<64, false, true><<<512, 512, LSTM_LDS_BYTES, stream>>>(
          Pbuf, whhB[l], src, cur, wlB[l], wrB[l], bl[l], nullptr, (float*)d_out, M, nltiles,
          tctr + 2);
    }
  }
}